// Round 10
// baseline (3782.205 us; speedup 1.0000x reference)
//
#include <hip/hip_runtime.h>
#include <hip/hip_bf16.h>

// 2-layer LSTM, B=64, F=128, T=1024, H=512. Output = h_T of layer 1 (64x512 fp32).
// R11: fat WGs (512 thr, 8 waves) on the proven R9 LLC protocol.
// R10 (XCD-local L2 coherence) burned 2 rounds with identical harness deaths ->
// treated as kernel-induced livelock risk (vote trusts HW_REG_XCC_ID; a false
// single-XCD vote caches a stale flag line forever). Shelved; NO vote, NO sc0-only
// path here -- pure R9 coherence (sc0sc1 LLC), which is placement-agnostic.
// Change vs R9: 64 -> 16 WGs per layer-group x4 threads each.
//   - barrier fan-in per group 64 -> 32 (straggler tail shrinks)
//   - LLC read herd halves: 16x16KB + 16x32KB per group per step (dedup now
//     across 8 waves instead of 4)
//   - all 32 group flags fit in 2 cache lines -> single coalesced poll load
//   - per-wave staging regs DROP (2 chunks/wave vs 8): L1 ~= 128 weight + 16
//     staging + ~50 misc < 256 -> 2 waves/SIMD fits (per-SIMD file 512/lane)
// Per-wave structure identical to R9: wave owns 4 cols, same weight frags, same
// gate reshuffle, same publish tile logic (tile now 16x32 cols).
// Kept: APAD=40 conflict-free staging (R9), LDS h dedup (R8b), fence-free
// sc0sc1 coherence (R6b), coalesced publish + layer-split slack flags (R7),
// 4 batch-groups (R5), reg-resident weights (R4).

#define B_ 64
#define F_ 128
#define T_ 1024
#define H_ 512
#define NWG 128
#define APAD 40   // staging inner dim (elements): 80B row stride, conflict-free

typedef __bf16 bf16x8 __attribute__((ext_vector_type(8)));
typedef float f32x4 __attribute__((ext_vector_type(4)));
typedef unsigned u32x4 __attribute__((ext_vector_type(4)));

__device__ __forceinline__ float sigm(float x) { return 1.0f / (1.0f + __expf(-x)); }
__device__ __forceinline__ float tanh_fast(float x) { return 1.0f - 2.0f / (__expf(2.0f * x) + 1.0f); }

// Coherence-point 16B load: bypass L1+L2, read LLC. Callers batch + drain once.
#define GLOAD_SC(dst, base, imm)                                      \
  asm volatile("global_load_dwordx4 %0, %1, off offset:%c2 sc0 sc1"   \
               : "=v"(dst) : "v"(base), "i"(imm))
// Coherence-point 16B store (write-through to LLC); ack drains at vmcnt(0).
#define GSTORE_SC(val, base)                                          \
  asm volatile("global_store_dwordx4 %0, %1, off sc0 sc1"             \
               :: "v"(base), "v"(val) : "memory")

// x (B,F,T) fp32 -> xT (T,B,F) bf16
__global__ __launch_bounds__(256) void transpose_x_kernel(const float* __restrict__ x,
                                                          __bf16* __restrict__ xT) {
  __shared__ float tile[F_][65];
  const int bb = blockIdx.x >> 4;
  const int tt = blockIdx.x & 15;
  const int tid = threadIdx.x;
  const int tl = tid & 63;
  const int f0 = tid >> 6;
  for (int fo = 0; fo < F_; fo += 4) {
    int f = fo + f0;
    tile[f][tl] = x[((size_t)bb * F_ + f) * T_ + tt * 64 + tl];
  }
  __syncthreads();
  const int fw = tid & 127;
  const int tg = tid >> 7;
  for (int to = 0; to < 64; to += 2) {
    int t = to + tg;
    xT[((size_t)(tt * 64 + t) * B_ + bb) * F_ + fw] = (__bf16)tile[fw][t];
  }
}

// arrive: __syncthreads drains all 8 waves' vmcnt (publish stores acked at LLC)
// before tid0 posts the monotone counter.
__device__ __forceinline__ void arrive_flag(unsigned* gfl, int wgl, int tid, unsigned tgt) {
  __syncthreads();
  if (tid == 0)
    __hip_atomic_store(&gfl[wgl], tgt, __ATOMIC_RELAXED, __HIP_MEMORY_SCOPE_AGENT);
}

// wait: 32 lanes of wave 0 poll the 32 group flags (2 cache lines, coalesced)
// with per-half targets (flags[0..16)=L0 WGs, [16..32)=L1 WGs). No acquire
// fence: all h reads are sc0sc1 coherence-point loads.
__device__ __forceinline__ void wait_split(unsigned* gfl, int tid, unsigned tgtL0, unsigned tgtL1) {
  if (tid < 32) {
    const unsigned tgt = (tid < 16) ? tgtL0 : tgtL1;
    while (__hip_atomic_load(&gfl[tid], __ATOMIC_RELAXED, __HIP_MEMORY_SCOPE_AGENT) < tgt)
      __builtin_amdgcn_s_sleep(1);
  }
  __syncthreads();
}

__global__ __launch_bounds__(512, 1) void lstm_persistent(
    const __bf16* __restrict__ xT,
    const float* __restrict__ Wih0, const float* __restrict__ Whh0,
    const float* __restrict__ bih0, const float* __restrict__ bhh0,
    const float* __restrict__ Wih1, const float* __restrict__ Whh1,
    const float* __restrict__ bih1, const float* __restrict__ bhh1,
    __bf16* h0_pub, __bf16* h1_pub,   // each: [4][B][H] bf16, 4-gen rotation
    unsigned* flags,                   // [4 groups][64] dword counters (32 used)
    float* __restrict__ out) {
  __shared__ float sG[8][288];                  // per-wave gate slab, stride 72
  __shared__ __align__(16) __bf16 sH[16][40];   // publish tile: 16 batches x 32 cols
  __shared__ __align__(16) __bf16 sA0[16][16][APAD];  // h0 staging [kc][b][col]
  __shared__ __align__(16) __bf16 sA1[16][16][APAD];  // h1 staging (layer-1)

  const int wg   = blockIdx.x;       // 0..127
  const int g    = wg & 3;           // batch group (XCDs {g,g+4} under %8 rr)
  const int wgl  = wg >> 2;          // 0..31 within group
  const int tid  = threadIdx.x;      // 0..511
  const int wv   = tid >> 6;         // 0..7
  const int lane = tid & 63;
  const int p    = lane >> 4;        // quad (= gate index for A/C rows)
  const int l15  = lane & 15;
  const int b    = g * 16 + l15;     // global batch
  const int ks   = p * 8;            // k offset inside a 32-chunk
  const int jw   = wgl & 15;         // column-block (32 cols) within layer
  const int col4 = jw * 32 + wv * 4; // this wave's 4 h-columns
  const int row  = (l15 >> 2) * H_ + col4 + (l15 & 3);  // A-frag gate row for m=l15
  unsigned* gfl  = flags + (g << 6);
  // publish-store lane mapping (tid<64): 4 lanes per batch row (64B), 16B each
  const int pb   = tid >> 2;         // batch within group
  const int phf  = tid & 3;          // which 16B chunk of the 64B row

  if (wgl < 16) {
    // ---------------- layer 0 ----------------
    bf16x8 wh[16], wi[4];
    {
      const float* s = Whh0 + (size_t)row * H_ + ks;
#pragma unroll
      for (int kc = 0; kc < 16; ++kc) {
        bf16x8 a;
#pragma unroll
        for (int jj = 0; jj < 8; ++jj) a[jj] = (__bf16)s[kc * 32 + jj];
        wh[kc] = a;
      }
      const float* si = Wih0 + (size_t)row * F_ + ks;
#pragma unroll
      for (int kc = 0; kc < 4; ++kc) {
        bf16x8 a;
#pragma unroll
        for (int jj = 0; jj < 8; ++jj) a[jj] = (__bf16)si[kc * 32 + jj];
        wi[kc] = a;
      }
    }
    float bq[4];
#pragma unroll
    for (int r = 0; r < 4; ++r) {
      const int grow = p * H_ + col4 + r;
      bq[r] = bih0[grow] + bhh0[grow];
    }

    float c0 = 0.f;
    // x contribution for it=0 (no barrier precedes; xT ready at launch)
    f32x4 accb = {0.f, 0.f, 0.f, 0.f};
    {
      const __bf16* xrow = xT + ((size_t)0 * B_ + b) * F_;
#pragma unroll
      for (int kc = 0; kc < 4; ++kc) {
        bf16x8 xb = *(const bf16x8*)&xrow[kc * 32 + ks];
        accb = __builtin_amdgcn_mfma_f32_16x16x32_bf16(wi[kc], xb, accb, 0, 0, 0);
      }
    }

    for (int it = 0; it < T_; ++it) {
      const __bf16* h0r = h0_pub + ((it + 3) & 3) * (B_ * H_);
      __bf16* h0w = h0_pub + (it & 3) * (B_ * H_);

      // ---- stage h0 slice through LDS (wave wv loads k-chunks [2wv,2wv+2)) ----
      {
        const __bf16* src = h0r + (size_t)b * H_ + wv * 64 + ks;
        bf16x8 st0, st1;
        GLOAD_SC(st0, src, 0);
        GLOAD_SC(st1, src, 64);
        asm volatile("s_waitcnt vmcnt(0)" ::: "memory");
        __builtin_amdgcn_sched_barrier(0);
        *(bf16x8*)&sA0[wv * 2 + 0][l15][ks] = st0;
        *(bf16x8*)&sA0[wv * 2 + 1][l15][ks] = st1;
      }
      __syncthreads();

      f32x4 acc = {0.f, 0.f, 0.f, 0.f};
#pragma unroll
      for (int kc = 0; kc < 16; ++kc) {
        bf16x8 hb = *(const bf16x8*)&sA0[kc][l15][ks];
        acc = __builtin_amdgcn_mfma_f32_16x16x32_bf16(wh[kc], hb, acc, 0, 0, 0);
      }

#pragma unroll
      for (int r = 0; r < 4; ++r) {
        float v = acc[r] + accb[r] + bq[r];
        sG[wv][p * 72 + r * 16 + l15] = (p == 2) ? tanh_fast(v) : sigm(v);
      }
      // sG slab is per-wave private: lgkmcnt ordering suffices, no barrier
      float gi = sG[wv][0 * 72 + p * 16 + l15];
      float gf = sG[wv][1 * 72 + p * 16 + l15];
      float gg = sG[wv][2 * 72 + p * 16 + l15];
      float go = sG[wv][3 * 72 + p * 16 + l15];
      c0 = gf * c0 + gi * gg;
      float h = go * tanh_fast(c0);

      // coalesced publish: stage WG tile (16 batches x 32 cols), wave0 stores
      sH[l15][wv * 4 + p] = (__bf16)h;
      __syncthreads();
      if (tid < 64) {
        u32x4 d = *(const u32x4*)&sH[pb][phf * 8];
        __bf16* dst = h0w + (size_t)(g * 16 + pb) * H_ + jw * 32 + phf * 8;
        GSTORE_SC(d, dst);
      }
      arrive_flag(gfl, wgl, tid, (unsigned)(it + 1));
      if (it + 1 < T_) {
        // next step's x-GEMM: loads+MFMA hidden under the peer wait
        const __bf16* xrow = xT + ((size_t)(it + 1) * B_ + b) * F_;
        f32x4 nb = {0.f, 0.f, 0.f, 0.f};
#pragma unroll
        for (int kc = 0; kc < 4; ++kc) {
          bf16x8 xb = *(const bf16x8*)&xrow[kc * 32 + ks];
          nb = __builtin_amdgcn_mfma_f32_16x16x32_bf16(wi[kc], xb, nb, 0, 0, 0);
        }
        accb = nb;
        // entering step t=it+1: L0 peers >= t; L1 >= t-2 (4-gen anti-overwrite)
        const unsigned tgtL1 = (it >= 1) ? (unsigned)(it - 1) : 0u;
        wait_split(gfl, tid, (unsigned)(it + 1), tgtL1);
      }
    }
  } else {
    // ---------------- layer 1 ----------------
    bf16x8 wi[16], wh[16];
    {
      const float* s0 = Wih1 + (size_t)row * H_ + ks;
      const float* s1 = Whh1 + (size_t)row * H_ + ks;
#pragma unroll
      for (int kc = 0; kc < 16; ++kc) {
        bf16x8 a, c;
#pragma unroll
        for (int jj = 0; jj < 8; ++jj) {
          a[jj] = (__bf16)s0[kc * 32 + jj];
          c[jj] = (__bf16)s1[kc * 32 + jj];
        }
        wi[kc] = a; wh[kc] = c;
      }
    }
    float bq[4];
#pragma unroll
    for (int r = 0; r < 4; ++r) {
      const int grow = p * H_ + col4 + r;
      bq[r] = bih1[grow] + bhh1[grow];
    }

    float c1 = 0.f;
    arrive_flag(gfl, wgl, tid, 1u);   // "step 0 done" (layer-1 idle that step)
    wait_split(gfl, tid, 1u, 1u);
    for (int it = 1; it <= T_; ++it) {
      const __bf16* h0r = h0_pub + ((it + 3) & 3) * (B_ * H_);
      const __bf16* h1r = h1_pub + ((it + 3) & 3) * (B_ * H_);
      __bf16* h1w = h1_pub + (it & 3) * (B_ * H_);

      // ---- stage h0+h1 slices through LDS (2 chunks each per wave) ----
      {
        const __bf16* sa = h0r + (size_t)b * H_ + wv * 64 + ks;
        const __bf16* sc = h1r + (size_t)b * H_ + wv * 64 + ks;
        bf16x8 sa0, sa1, sc0, sc1_;
        GLOAD_SC(sa0, sa, 0);
        GLOAD_SC(sa1, sa, 64);
        GLOAD_SC(sc0, sc, 0);
        GLOAD_SC(sc1_, sc, 64);
        asm volatile("s_waitcnt vmcnt(0)" ::: "memory");
        __builtin_amdgcn_sched_barrier(0);
        *(bf16x8*)&sA0[wv * 2 + 0][l15][ks] = sa0;
        *(bf16x8*)&sA0[wv * 2 + 1][l15][ks] = sa1;
        *(bf16x8*)&sA1[wv * 2 + 0][l15][ks] = sc0;
        *(bf16x8*)&sA1[wv * 2 + 1][l15][ks] = sc1_;
      }
      __syncthreads();

      f32x4 acca = {0.f, 0.f, 0.f, 0.f};
      f32x4 accc = {0.f, 0.f, 0.f, 0.f};
#pragma unroll
      for (int kc = 0; kc < 16; ++kc) {
        bf16x8 ha = *(const bf16x8*)&sA0[kc][l15][ks];
        bf16x8 hc = *(const bf16x8*)&sA1[kc][l15][ks];
        acca = __builtin_amdgcn_mfma_f32_16x16x32_bf16(wi[kc], ha, acca, 0, 0, 0);
        accc = __builtin_amdgcn_mfma_f32_16x16x32_bf16(wh[kc], hc, accc, 0, 0, 0);
      }
#pragma unroll
      for (int r = 0; r < 4; ++r) {
        float v = acca[r] + accc[r] + bq[r];
        sG[wv][p * 72 + r * 16 + l15] = (p == 2) ? tanh_fast(v) : sigm(v);
      }
      float gi = sG[wv][0 * 72 + p * 16 + l15];
      float gf = sG[wv][1 * 72 + p * 16 + l15];
      float gg = sG[wv][2 * 72 + p * 16 + l15];
      float go = sG[wv][3 * 72 + p * 16 + l15];
      c1 = gf * c1 + gi * gg;
      float h = go * tanh_fast(c1);

      if (it < T_) {
        // coalesced publish of h1 tile
        sH[l15][wv * 4 + p] = (__bf16)h;
        __syncthreads();
        if (tid < 64) {
          u32x4 d = *(const u32x4*)&sH[pb][phf * 8];
          __bf16* dst = h1w + (size_t)(g * 16 + pb) * H_ + jw * 32 + phf * 8;
          GSTORE_SC(d, dst);
        }
        arrive_flag(gfl, wgl, tid, (unsigned)(it + 1));
        // entering step it+1: need h0(it) => L0 >= it+1; h1 peers >= it+1
        wait_split(gfl, tid, (unsigned)(it + 1), (unsigned)(it + 1));
      } else {
        out[b * H_ + col4 + p] = h;   // final h1[T-1], fp32
      }
    }
  }
}

// Workspace layout:
//   [0]        flags: 4 groups x 64 x 4B = 1 KiB (16 KiB reserved; 32/group used)
//   [16384]    h0_pub: 4 gens x 64x512x2B = 262144 B
//   [278528]   h1_pub: 262144 B
//   [1 MiB]    xT: 16 MiB
// Zeroed region: [0, 540672).
extern "C" void kernel_launch(void* const* d_in, const int* in_sizes, int n_in,
                              void* d_out, int out_size, void* d_ws, size_t ws_size,
                              hipStream_t stream) {
  const float* x    = (const float*)d_in[0];
  const float* Wih0 = (const float*)d_in[1];
  const float* Whh0 = (const float*)d_in[2];
  const float* bih0 = (const float*)d_in[3];
  const float* bhh0 = (const float*)d_in[4];
  const float* Wih1 = (const float*)d_in[5];
  const float* Whh1 = (const float*)d_in[6];
  const float* bih1 = (const float*)d_in[7];
  const float* bhh1 = (const float*)d_in[8];
  float* out = (float*)d_out;

  char* ws = (char*)d_ws;
  unsigned* flags = (unsigned*)ws;
  __bf16* h0p = (__bf16*)(ws + 16384);
  __bf16* h1p = (__bf16*)(ws + 16384 + 4 * B_ * H_ * 2);
  __bf16* xT  = (__bf16*)(ws + (1 << 20));

  hipMemsetAsync(ws, 0, 16384 + 8 * B_ * H_ * 2, stream);

  transpose_x_kernel<<<dim3(B_ * 16), dim3(256), 0, stream>>>(x, xT);

  lstm_persistent<<<dim3(NWG), dim3(512), 0, stream>>>(
      xT, Wih0, Whh0, bih0, bhh0, Wih1, Whh1, bih1, bhh1,
      h0p, h1p, flags, out);
}